// Round 15
// baseline (131.273 us; speedup 1.0000x reference)
//
#include <hip/hip_runtime.h>

#define NSAMP 2048
#define DIM 1024
#define NCLS 224
#define PERCLS 224
#define CH 32                             // samples per chunk (4-wave blocks)
#define KSL 256                           // k per slice
#define NSLICE 4
#define BOTBLKS (NCLS * NSLICE)           // 896 (dispatched first: longer blocks)
#define TOPBLKS ((NSAMP / CH) * NSLICE)   // 256
#define NTILE 32                          // 8 k-rows per tile
#define TILE_B 7168                       // 8 * 224 * 4 bytes
#define SLOT_F 2048                       // floats per ring slot (8192 B)

struct Ws {
  int cls[NSAMP];
  int within[NSAMP];
  int order[NSAMP];
  int offsets[NCLS + 1];
  int pad_[3];
  float top_part[NSLICE][NSAMP][NCLS];
  float bot_part[NSLICE][NSAMP][PERCLS];
};

// ---------------- prep ----------------
__global__ __launch_bounds__(256) void prep_kernel(const int* __restrict__ target,
                                                   Ws* __restrict__ ws) {
  __shared__ int cnt[NCLS];
  __shared__ int cur[NCLS];
  __shared__ int sc[256];
  int tid = threadIdx.x;
  for (int c = tid; c < NCLS; c += 256) cnt[c] = 0;
  __syncthreads();
  for (int n = tid; n < NSAMP; n += 256) {
    int t = target[n];
    int c = t / PERCLS;
    ws->cls[n] = c;
    ws->within[n] = t - c * PERCLS;
    atomicAdd(&cnt[c], 1);
  }
  __syncthreads();
  int v = (tid < NCLS) ? cnt[tid] : 0;
  sc[tid] = v;
  __syncthreads();
  for (int off = 1; off < 256; off <<= 1) {
    int a = (tid >= off) ? sc[tid - off] : 0;
    __syncthreads();
    sc[tid] += a;
    __syncthreads();
  }
  if (tid < NCLS) {
    int excl = sc[tid] - cnt[tid];
    ws->offsets[tid] = excl;
    cur[tid] = excl;
  }
  if (tid == 0) ws->offsets[NCLS] = NSAMP;
  __syncthreads();
  for (int n = tid; n < NSAMP; n += 256) {
    int c = ws->cls[n];
    int pos = atomicAdd(&cur[c], 1);
    ws->order[pos] = n;
  }
}

// ---------------- partial: CH=32, gll ring-4 distance-3 -----------------------
// 256 thr = 4 waves (8 samples each); lane<56 owns 4 cols (float4).
// Weight slice (256k x 224c) = 32 tiles x 8 rows (7168 B). 4-slot LDS ring,
// staged 3 tiles ahead (2 gll/wave/tile), counted vmcnt(4) + raw s_barrier.
// CH=32 halves top re-streaming (59 MB) and makes 16<K<=32 classes
// single-pass; streamed total 351 -> 266 MB at unchanged residency.
__global__ __launch_bounds__(256) void partial_kernel(const float* __restrict__ x,
                                                      const float* __restrict__ tw,
                                                      const float* __restrict__ bw,
                                                      Ws* __restrict__ ws) {
  __shared__ float xs[CH][KSL];        // 32 KB
  __shared__ float wl[4 * SLOT_F];     // 32 KB ring
  const int tid = threadIdx.x;
  const int lane = tid & 63;
  const int wv = tid >> 6;             // wave 0..3 = samples wv*8..wv*8+7
  const int bid = blockIdx.x;

  const bool is_bot = bid < BOTBLKS;
  int n0 = 0, c = 0, bs, start = 0, K = CH;
  if (is_bot) {
    bs = bid & 3;
    c = bid >> 2;
    start = ws->offsets[c];
    K = ws->offsets[c + 1] - start;
    if (K == 0) return;
  } else {
    int b = bid - BOTBLKS;
    bs = b & 3;
    n0 = (b >> 2) * CH;
  }
  const float* Wslice = is_bot
      ? (bw + (size_t)c * (DIM * PERCLS) + (size_t)(bs * KSL) * PERCLS)
      : (tw + (size_t)(bs * KSL) * NCLS);

  typedef const __attribute__((address_space(1))) unsigned int gu32;
  typedef __attribute__((address_space(3))) unsigned int lu32;

  // stage tile t: 8 glls (2 per wave) of 1024 B; unit 7 is pad (src clamped)
  auto stage_tile = [&](int t) {
    const char* base = (const char*)Wslice + (size_t)t * TILE_B;
    float* slot = &wl[(t & 3) * SLOT_F];
#pragma unroll
    for (int j = 0; j < 2; ++j) {
      int u = wv * 2 + j;
      int off = u * 1024 + lane * 16;
      int soff = (off < TILE_B) ? off : (off - 1024);   // clamp pad unit
      __builtin_amdgcn_global_load_lds((gu32*)(base + soff),
                                       (lu32*)(slot + u * 256), 16, 0, 0);
    }
  };

  float4 acc[8];

  auto compute_tile = [&](int t) {
    if (lane < 56) {
      const float* slot = &wl[(t & 3) * SLOT_F];
#pragma unroll
      for (int g = 0; g < 2; ++g) {      // 4 k-rows per g
        float4 w0 = *(const float4*)&slot[(g * 4 + 0) * 224 + lane * 4];
        float4 w1 = *(const float4*)&slot[(g * 4 + 1) * 224 + lane * 4];
        float4 w2 = *(const float4*)&slot[(g * 4 + 2) * 224 + lane * 4];
        float4 w3 = *(const float4*)&slot[(g * 4 + 3) * 224 + lane * 4];
#pragma unroll
        for (int s = 0; s < 8; ++s) {
          float4 xv = *(const float4*)&xs[wv * 8 + s][t * 8 + g * 4];
          acc[s].x = fmaf(xv.x, w0.x, acc[s].x);
          acc[s].y = fmaf(xv.x, w0.y, acc[s].y);
          acc[s].z = fmaf(xv.x, w0.z, acc[s].z);
          acc[s].w = fmaf(xv.x, w0.w, acc[s].w);
          acc[s].x = fmaf(xv.y, w1.x, acc[s].x);
          acc[s].y = fmaf(xv.y, w1.y, acc[s].y);
          acc[s].z = fmaf(xv.y, w1.z, acc[s].z);
          acc[s].w = fmaf(xv.y, w1.w, acc[s].w);
          acc[s].x = fmaf(xv.z, w2.x, acc[s].x);
          acc[s].y = fmaf(xv.z, w2.y, acc[s].y);
          acc[s].z = fmaf(xv.z, w2.z, acc[s].z);
          acc[s].w = fmaf(xv.z, w2.w, acc[s].w);
          acc[s].x = fmaf(xv.w, w3.x, acc[s].x);
          acc[s].y = fmaf(xv.w, w3.y, acc[s].y);
          acc[s].z = fmaf(xv.w, w3.z, acc[s].z);
          acc[s].w = fmaf(xv.w, w3.w, acc[s].w);
        }
      }
    }
  };

  for (int chunk = 0; chunk < K; chunk += CH) {
    const int S = min(CH, K - chunk);
    __syncthreads();   // xs / wl free from previous chunk

    // stage x: 2048 float4 (32 KB), 8 per thread, coalesced
#pragma unroll
    for (int pass = 0; pass < 8; ++pass) {
      int i = tid + pass * 256;
      int ss = i >> 6;
      int q = i & 63;
      int n;
      if (is_bot) n = ws->order[start + min(chunk + ss, K - 1)];
      else        n = n0 + ss;
      ((float4*)xs)[i] = *(const float4*)(x + (size_t)n * DIM + bs * KSL + q * 4);
    }
    __syncthreads();   // x visible; drains x loads (no glls outstanding yet)

#pragma unroll
    for (int s = 0; s < 8; ++s) acc[s] = make_float4(0.f, 0.f, 0.f, 0.f);

    // ring prologue: 3 tiles in flight (6 glls per wave)
    stage_tile(0);
    stage_tile(1);
    stage_tile(2);

    for (int t = 0; t < NTILE - 3; ++t) {
      asm volatile("s_waitcnt vmcnt(4)" ::: "memory");   // my tile-t glls done
      __builtin_amdgcn_sched_barrier(0);
      __builtin_amdgcn_s_barrier();                      // peers' tile-t done too
      __builtin_amdgcn_sched_barrier(0);
      stage_tile(t + 3);                                 // slot (t+3)&3 != t..t+2
      compute_tile(t);
    }
    asm volatile("s_waitcnt vmcnt(4)" ::: "memory");
    __builtin_amdgcn_sched_barrier(0);
    __builtin_amdgcn_s_barrier();
    __builtin_amdgcn_sched_barrier(0);
    compute_tile(NTILE - 3);
    asm volatile("s_waitcnt vmcnt(2)" ::: "memory");
    __builtin_amdgcn_sched_barrier(0);
    __builtin_amdgcn_s_barrier();
    __builtin_amdgcn_sched_barrier(0);
    compute_tile(NTILE - 2);
    asm volatile("s_waitcnt vmcnt(0)" ::: "memory");
    __builtin_amdgcn_sched_barrier(0);
    __builtin_amdgcn_s_barrier();
    __builtin_amdgcn_sched_barrier(0);
    compute_tile(NTILE - 1);

    // write partials (thread owns its 4 cols; 16B-aligned)
    if (lane < 56) {
      if (is_bot) {
#pragma unroll
        for (int s = 0; s < 8; ++s) {
          int sl = wv * 8 + s;
          if (sl < S) {
            int n = ws->order[start + chunk + sl];
            *(float4*)&ws->bot_part[bs][n][lane * 4] = acc[s];
          }
        }
      } else {
#pragma unroll
        for (int s = 0; s < 8; ++s)
          *(float4*)&ws->top_part[bs][n0 + wv * 8 + s][lane * 4] = acc[s];
      }
    }
  }
}

// ---------------- final ----------------
__global__ __launch_bounds__(256) void final_kernel(const float* __restrict__ tb,
                                                    const float* __restrict__ bb,
                                                    const Ws* __restrict__ ws,
                                                    float* __restrict__ out) {
  __shared__ float lt[8][NCLS];
  __shared__ float lb[8][NCLS];
  const int tid = threadIdx.x;
  const int n0 = blockIdx.x * 8;
  const int p = tid;

  if (p < NCLS) {
    float tbias = tb[p];
#pragma unroll
    for (int s = 0; s < 8; ++s) {
      int n = n0 + s;
      int c = ws->cls[n];
      float t = tbias;
      float b = bb[(size_t)c * PERCLS + p];
#pragma unroll
      for (int dc = 0; dc < NSLICE; ++dc) t += ws->top_part[dc][n][p];
#pragma unroll
      for (int dc = 0; dc < NSLICE; ++dc) b += ws->bot_part[dc][n][p];
      lt[s][p] = t;
      lb[s][p] = b;
    }
  }
  __syncthreads();

  const int wv = tid >> 6, lane = tid & 63;
  for (int s = wv * 2; s < wv * 2 + 2; ++s) {
    const int n = n0 + s;
    float v[4], mx = -INFINITY;
#pragma unroll
    for (int j = 0; j < 4; ++j) {
      int pp = lane + 64 * j;
      v[j] = (pp < NCLS) ? lt[s][pp] : -INFINITY;
      mx = fmaxf(mx, v[j]);
    }
#pragma unroll
    for (int m = 32; m >= 1; m >>= 1) mx = fmaxf(mx, __shfl_xor(mx, m));
    float sum = 0.f;
#pragma unroll
    for (int j = 0; j < 4; ++j) {
      int pp = lane + 64 * j;
      if (pp < NCLS) sum += expf(v[j] - mx);
    }
#pragma unroll
    for (int m = 32; m >= 1; m >>= 1) sum += __shfl_xor(sum, m);
    float pt = expf(lt[s][ws->cls[n]] - mx) / sum;

    float mb = -INFINITY;
#pragma unroll
    for (int j = 0; j < 4; ++j) {
      int pp = lane + 64 * j;
      v[j] = (pp < NCLS) ? lb[s][pp] : -INFINITY;
      mb = fmaxf(mb, v[j]);
    }
#pragma unroll
    for (int m = 32; m >= 1; m >>= 1) mb = fmaxf(mb, __shfl_xor(mb, m));
    float sb = 0.f;
#pragma unroll
    for (int j = 0; j < 4; ++j) {
      int pp = lane + 64 * j;
      if (pp < NCLS) sb += expf(v[j] - mb);
    }
#pragma unroll
    for (int m = 32; m >= 1; m >>= 1) sb += __shfl_xor(sb, m);
    float pb = expf(lb[s][ws->within[n]] - mb) / sb;

    if (lane == 0) out[n] = pt * pb;
  }
}

extern "C" void kernel_launch(void* const* d_in, const int* in_sizes, int n_in,
                              void* d_out, int out_size, void* d_ws, size_t ws_size,
                              hipStream_t stream) {
  const float* x  = (const float*)d_in[0];
  const int* tgt  = (const int*)d_in[1];
  const float* tw = (const float*)d_in[2];
  const float* tb = (const float*)d_in[3];
  const float* bw = (const float*)d_in[4];
  const float* bb = (const float*)d_in[5];
  float* out = (float*)d_out;
  Ws* ws = (Ws*)d_ws;

  prep_kernel<<<1, 256, 0, stream>>>(tgt, ws);
  partial_kernel<<<BOTBLKS + TOPBLKS, 256, 0, stream>>>(x, tw, bw, ws);
  final_kernel<<<NSAMP / 8, 256, 0, stream>>>(tb, bb, ws, out);
}

// Round 16
// 84.520 us; speedup vs baseline: 1.5532x; 1.5532x over previous
//
#include <hip/hip_runtime.h>

#define NSAMP 2048
#define DIM 1024
#define NCLS 224
#define PERCLS 224
#define CH 16
#define KSL 256                           // k per slice
#define NSLICE 4
#define BOTBLKS (NCLS * NSLICE)           // 896 (dispatched first: longer blocks)
#define TOPBLKS ((NSAMP / CH) * NSLICE)   // 512
#define NTILE 32                          // 8 k-rows per tile
#define TILE_B 7168                       // 8 * 224 * 4 bytes
#define SLOT_F 2048                       // floats per ring slot (8192 B)

struct Ws {
  int cls[NSAMP];
  int within[NSAMP];
  int order[NSAMP];
  int offsets[NCLS + 1];
  int pad_[3];
  float top_part[NSLICE][NSAMP][NCLS];
  float bot_part[NSLICE][NSAMP][PERCLS];
};

// ---------------- prep ----------------
__global__ __launch_bounds__(256) void prep_kernel(const int* __restrict__ target,
                                                   Ws* __restrict__ ws) {
  __shared__ int cnt[NCLS];
  __shared__ int cur[NCLS];
  __shared__ int sc[256];
  int tid = threadIdx.x;
  for (int c = tid; c < NCLS; c += 256) cnt[c] = 0;
  __syncthreads();
  for (int n = tid; n < NSAMP; n += 256) {
    int t = target[n];
    int c = t / PERCLS;
    ws->cls[n] = c;
    ws->within[n] = t - c * PERCLS;
    atomicAdd(&cnt[c], 1);
  }
  __syncthreads();
  int v = (tid < NCLS) ? cnt[tid] : 0;
  sc[tid] = v;
  __syncthreads();
  for (int off = 1; off < 256; off <<= 1) {
    int a = (tid >= off) ? sc[tid - off] : 0;
    __syncthreads();
    sc[tid] += a;
    __syncthreads();
  }
  if (tid < NCLS) {
    int excl = sc[tid] - cnt[tid];
    ws->offsets[tid] = excl;
    cur[tid] = excl;
  }
  if (tid == 0) ws->offsets[NCLS] = NSAMP;
  __syncthreads();
  for (int n = tid; n < NSAMP; n += 256) {
    int c = ws->cls[n];
    int pos = atomicAdd(&cur[c], 1);
    ws->order[pos] = n;
  }
}

// ---------------- partial: R12 ring-3 + glls-across-prologue-barrier ----------
// 128 thr = 2 waves (8 samples each); lane<56 owns 4 cols (float4).
// Weight slice (256k x 224c) = 32 tiles x 8 rows (7168 B). 3-slot LDS ring,
// staged 2 tiles ahead via gll (4 gll/wave/tile), counted vmcnt(4) + raw
// s_barrier per tile. CHANGE vs R12: tiles 0,1 are issued BEFORE the x-ready
// barrier (lgkmcnt(0)+s_barrier instead of __syncthreads), so the ring never
// drains to empty between chunks -- no uncovered refill latency.
__global__ __launch_bounds__(128) void partial_kernel(const float* __restrict__ x,
                                                      const float* __restrict__ tw,
                                                      const float* __restrict__ bw,
                                                      Ws* __restrict__ ws) {
  __shared__ float xs[CH][KSL];        // 16 KB
  __shared__ float wl[3 * SLOT_F];     // 24 KB ring
  const int tid = threadIdx.x;
  const int lane = tid & 63;
  const int wv = tid >> 6;             // wave 0/1 = samples wv*8..wv*8+7
  const int bid = blockIdx.x;

  const bool is_bot = bid < BOTBLKS;
  int n0 = 0, c = 0, bs, start = 0, K = CH;
  if (is_bot) {
    bs = bid & 3;
    c = bid >> 2;
    start = ws->offsets[c];
    K = ws->offsets[c + 1] - start;
    if (K == 0) return;
  } else {
    int b = bid - BOTBLKS;
    bs = b & 3;
    n0 = (b >> 2) * CH;
  }
  const float* Wslice = is_bot
      ? (bw + (size_t)c * (DIM * PERCLS) + (size_t)(bs * KSL) * PERCLS)
      : (tw + (size_t)(bs * KSL) * NCLS);

  typedef const __attribute__((address_space(1))) unsigned int gu32;
  typedef __attribute__((address_space(3))) unsigned int lu32;

  // stage tile t: 8 glls (4 per wave) of 1024 B; unit 7 is pad (src clamped)
  auto stage_tile = [&](int t) {
    const char* base = (const char*)Wslice + (size_t)t * TILE_B;
    float* slot = &wl[(t % 3) * SLOT_F];
#pragma unroll
    for (int j = 0; j < 4; ++j) {
      int u = wv * 4 + j;
      int off = u * 1024 + lane * 16;
      int soff = (off < TILE_B) ? off : (off - 1024);   // clamp pad unit
      __builtin_amdgcn_global_load_lds((gu32*)(base + soff),
                                       (lu32*)(slot + u * 256), 16, 0, 0);
    }
  };

  float4 acc[8];

  auto compute_tile = [&](int t) {
    if (lane < 56) {
      const float* slot = &wl[(t % 3) * SLOT_F];
#pragma unroll
      for (int g = 0; g < 2; ++g) {      // 4 k-rows per g
        float4 w0 = *(const float4*)&slot[(g * 4 + 0) * 224 + lane * 4];
        float4 w1 = *(const float4*)&slot[(g * 4 + 1) * 224 + lane * 4];
        float4 w2 = *(const float4*)&slot[(g * 4 + 2) * 224 + lane * 4];
        float4 w3 = *(const float4*)&slot[(g * 4 + 3) * 224 + lane * 4];
#pragma unroll
        for (int s = 0; s < 8; ++s) {
          float4 xv = *(const float4*)&xs[wv * 8 + s][t * 8 + g * 4];
          acc[s].x = fmaf(xv.x, w0.x, acc[s].x);
          acc[s].y = fmaf(xv.x, w0.y, acc[s].y);
          acc[s].z = fmaf(xv.x, w0.z, acc[s].z);
          acc[s].w = fmaf(xv.x, w0.w, acc[s].w);
          acc[s].x = fmaf(xv.y, w1.x, acc[s].x);
          acc[s].y = fmaf(xv.y, w1.y, acc[s].y);
          acc[s].z = fmaf(xv.y, w1.z, acc[s].z);
          acc[s].w = fmaf(xv.y, w1.w, acc[s].w);
          acc[s].x = fmaf(xv.z, w2.x, acc[s].x);
          acc[s].y = fmaf(xv.z, w2.y, acc[s].y);
          acc[s].z = fmaf(xv.z, w2.z, acc[s].z);
          acc[s].w = fmaf(xv.z, w2.w, acc[s].w);
          acc[s].x = fmaf(xv.w, w3.x, acc[s].x);
          acc[s].y = fmaf(xv.w, w3.y, acc[s].y);
          acc[s].z = fmaf(xv.w, w3.z, acc[s].z);
          acc[s].w = fmaf(xv.w, w3.w, acc[s].w);
        }
      }
    }
  };

  for (int chunk = 0; chunk < K; chunk += CH) {
    const int S = min(CH, K - chunk);
    __syncthreads();   // xs / wl free from previous chunk (epilogue drained vmcnt)

    // stage x: 1024 float4 (16 KB), 8 per thread, coalesced.
    // Compiler retires each load before its ds_write -> vmcnt==0 afterwards.
#pragma unroll
    for (int pass = 0; pass < 8; ++pass) {
      int i = tid + pass * 128;
      int ss = i >> 6;
      int q = i & 63;
      int n;
      if (is_bot) n = ws->order[start + min(chunk + ss, K - 1)];
      else        n = n0 + ss;
      ((float4*)xs)[i] = *(const float4*)(x + (size_t)n * DIM + bs * KSL + q * 4);
    }

    // ring prologue BEFORE the barrier: 2 tiles (8 glls/wave) fly across it
    stage_tile(0);
    stage_tile(1);
    asm volatile("s_waitcnt lgkmcnt(0)" ::: "memory");  // xs ds_writes done
    __builtin_amdgcn_sched_barrier(0);
    __builtin_amdgcn_s_barrier();                       // xs visible block-wide
    __builtin_amdgcn_sched_barrier(0);

#pragma unroll
    for (int s = 0; s < 8; ++s) acc[s] = make_float4(0.f, 0.f, 0.f, 0.f);

    for (int t = 0; t < NTILE - 2; ++t) {
      asm volatile("s_waitcnt vmcnt(4)" ::: "memory");   // my tile-t glls done
      __builtin_amdgcn_sched_barrier(0);
      __builtin_amdgcn_s_barrier();                      // peers' tile-t done too
      __builtin_amdgcn_sched_barrier(0);
      stage_tile(t + 2);                                 // slot (t+2)%3 != t%3
      compute_tile(t);
    }
    asm volatile("s_waitcnt vmcnt(4)" ::: "memory");
    __builtin_amdgcn_sched_barrier(0);
    __builtin_amdgcn_s_barrier();
    __builtin_amdgcn_sched_barrier(0);
    compute_tile(NTILE - 2);
    asm volatile("s_waitcnt vmcnt(0)" ::: "memory");
    __builtin_amdgcn_sched_barrier(0);
    __builtin_amdgcn_s_barrier();
    __builtin_amdgcn_sched_barrier(0);
    compute_tile(NTILE - 1);

    // write partials (thread owns its 4 cols; 16B-aligned)
    if (lane < 56) {
      if (is_bot) {
#pragma unroll
        for (int s = 0; s < 8; ++s) {
          int sl = wv * 8 + s;
          if (sl < S) {
            int n = ws->order[start + chunk + sl];
            *(float4*)&ws->bot_part[bs][n][lane * 4] = acc[s];
          }
        }
      } else {
#pragma unroll
        for (int s = 0; s < 8; ++s)
          *(float4*)&ws->top_part[bs][n0 + wv * 8 + s][lane * 4] = acc[s];
      }
    }
  }
}

// ---------------- final ----------------
__global__ __launch_bounds__(256) void final_kernel(const float* __restrict__ tb,
                                                    const float* __restrict__ bb,
                                                    const Ws* __restrict__ ws,
                                                    float* __restrict__ out) {
  __shared__ float lt[8][NCLS];
  __shared__ float lb[8][NCLS];
  const int tid = threadIdx.x;
  const int n0 = blockIdx.x * 8;
  const int p = tid;

  if (p < NCLS) {
    float tbias = tb[p];
#pragma unroll
    for (int s = 0; s < 8; ++s) {
      int n = n0 + s;
      int c = ws->cls[n];
      float t = tbias;
      float b = bb[(size_t)c * PERCLS + p];
#pragma unroll
      for (int dc = 0; dc < NSLICE; ++dc) t += ws->top_part[dc][n][p];
#pragma unroll
      for (int dc = 0; dc < NSLICE; ++dc) b += ws->bot_part[dc][n][p];
      lt[s][p] = t;
      lb[s][p] = b;
    }
  }
  __syncthreads();

  const int wv = tid >> 6, lane = tid & 63;
  for (int s = wv * 2; s < wv * 2 + 2; ++s) {
    const int n = n0 + s;
    float v[4], mx = -INFINITY;
#pragma unroll
    for (int j = 0; j < 4; ++j) {
      int pp = lane + 64 * j;
      v[j] = (pp < NCLS) ? lt[s][pp] : -INFINITY;
      mx = fmaxf(mx, v[j]);
    }
#pragma unroll
    for (int m = 32; m >= 1; m >>= 1) mx = fmaxf(mx, __shfl_xor(mx, m));
    float sum = 0.f;
#pragma unroll
    for (int j = 0; j < 4; ++j) {
      int pp = lane + 64 * j;
      if (pp < NCLS) sum += expf(v[j] - mx);
    }
#pragma unroll
    for (int m = 32; m >= 1; m >>= 1) sum += __shfl_xor(sum, m);
    float pt = expf(lt[s][ws->cls[n]] - mx) / sum;

    float mb = -INFINITY;
#pragma unroll
    for (int j = 0; j < 4; ++j) {
      int pp = lane + 64 * j;
      v[j] = (pp < NCLS) ? lb[s][pp] : -INFINITY;
      mb = fmaxf(mb, v[j]);
    }
#pragma unroll
    for (int m = 32; m >= 1; m >>= 1) mb = fmaxf(mb, __shfl_xor(mb, m));
    float sb = 0.f;
#pragma unroll
    for (int j = 0; j < 4; ++j) {
      int pp = lane + 64 * j;
      if (pp < NCLS) sb += expf(v[j] - mb);
    }
#pragma unroll
    for (int m = 32; m >= 1; m >>= 1) sb += __shfl_xor(sb, m);
    float pb = expf(lb[s][ws->within[n]] - mb) / sb;

    if (lane == 0) out[n] = pt * pb;
  }
}

extern "C" void kernel_launch(void* const* d_in, const int* in_sizes, int n_in,
                              void* d_out, int out_size, void* d_ws, size_t ws_size,
                              hipStream_t stream) {
  const float* x  = (const float*)d_in[0];
  const int* tgt  = (const int*)d_in[1];
  const float* tw = (const float*)d_in[2];
  const float* tb = (const float*)d_in[3];
  const float* bw = (const float*)d_in[4];
  const float* bb = (const float*)d_in[5];
  float* out = (float*)d_out;
  Ws* ws = (Ws*)d_ws;

  prep_kernel<<<1, 256, 0, stream>>>(tgt, ws);
  partial_kernel<<<BOTBLKS + TOPBLKS, 128, 0, stream>>>(x, tw, bw, ws);
  final_kernel<<<NSAMP / 8, 256, 0, stream>>>(tb, bb, ws, out);
}